// Round 10
// baseline (122.380 us; speedup 1.0000x reference)
//
#include <hip/hip_runtime.h>

// CCN_2D on MI355X. N=256 vertices, K=16, C0=16, H=32.
// Facts (validated by exact passes R1-R9):
//  * CH rows one-hot => T_t[a][b][c] = Fin[j_t, P_t[a], P_t[b], c].
//  * A = I_16 collapses contract18 to 6 effective weight matrices.
//  * P_t[t] = -1 (no self-loops) => c17 / d_ttt terms vanish.
//  * Layer-1 input is broadcast of X => rank-1 closed form, no gathers.
//  * F1 channel-interleaved: chunk (i*16+q)*128 + c4*16 + p holds channels
//    4c4..4c4+3 of F1[i][p][q][:] (16 B stride on lane-varying p).
// R9 lesson: totals track launch count/structure, not kernel internals
// (spill & icache theories falsified). This round: ONE plain launch.
// l1 -> per-vertex release flag; l2 acquire-spins on its 16 neighbors only
// (no grid barrier, l1-tail overlaps l2-head). All 256 blocks co-resident
// (LDS 63 KB -> >=2 blocks/CU capacity) => flag handshake is deadlock-free.
// MAGIC != 0xAA poison, so flags need no pre-zeroing.

constexpr int KN = 16, HH = 32, NV = 256, C2 = 32;
constexpr unsigned MAGIC = 0x5A5A5A5Au;

__device__ __forceinline__ float rlane(float v, int l) {
    return __int_as_float(__builtin_amdgcn_readlane(__float_as_int(v), l));
}

#define MM_RL(WPTR, NB, COEF_EXPR, ACC) do {                                   \
    _Pragma("unroll")                                                          \
    for (int B = 0; B < (NB); ++B) {                                           \
        const float4 w_ = ((const float4*)(WPTR))[B * 64 + lane];              \
        _Pragma("unroll")                                                      \
        for (int cc = 0; cc < 8; ++cc) {                                       \
            const int ci = B * 8 + cc;                                         \
            const float cf_ = (COEF_EXPR);                                     \
            _Pragma("unroll")                                                  \
            for (int h4 = 0; h4 < 8; ++h4) {                                   \
                const int src_ = 8 * cc + h4;                                  \
                (ACC)[4*h4+0] = fmaf(cf_, rlane(w_.x, src_), (ACC)[4*h4+0]);   \
                (ACC)[4*h4+1] = fmaf(cf_, rlane(w_.y, src_), (ACC)[4*h4+1]);   \
                (ACC)[4*h4+2] = fmaf(cf_, rlane(w_.z, src_), (ACC)[4*h4+2]);   \
                (ACC)[4*h4+3] = fmaf(cf_, rlane(w_.w, src_), (ACC)[4*h4+3]);   \
            }                                                                  \
        }                                                                      \
    }                                                                          \
} while (0)

struct Phase1 {
    float sE1[6 * 512];
    float sPP[256 * 36];
    float sX[16][20];
    float sV[16][164];
    int   s_nbi[16];
    int   s_nbj[16][17];
    int   s_P[16][16];
    int   s_vm[16];
    float s_m[16];
};
struct Phase2 {
    float sE2[6 * 1024];
    float sRpp[256 * 36];
    float s_stb[16 * 33];
    float s_sall[C2];
    int   s_nbi[16];
    int   s_PQ[16 * 17];
    float s_red[4];
};
union SMem { Phase1 p1; Phase2 p2; };

__global__ __launch_bounds__(512)
void ccn_fused(const float* __restrict__ X, const int* __restrict__ nbrs,
               const float* __restrict__ W1, const float* __restrict__ b1,
               const float* __restrict__ W2, const float* __restrict__ b2,
               const float* __restrict__ fcw, const float* __restrict__ fcb,
               float* __restrict__ F1c, unsigned* __restrict__ flags,
               float* __restrict__ partials, unsigned* __restrict__ dflags,
               float* __restrict__ out)
{
    __shared__ __align__(16) SMem sm;
    __shared__ float s_fin[8];

    const int tid  = threadIdx.x;
    const int i    = ((blockIdx.x & 7) << 5) | (blockIdx.x >> 3);  // XCD swizzle
    const int lane = tid & 63;

    // ================= phase 1: layer 1 (R8 body) =================
    {
        Phase1& P = sm.p1;
        if (tid < 16) P.s_nbi[tid] = nbrs[i * 16 + tid];
        __syncthreads();

        if (tid < 256) {
            const int t = tid >> 4, y = tid & 15;
            const int j = P.s_nbi[t];
            P.s_nbj[t][y] = nbrs[j * 16 + y];
            P.sX[t][y]    = X[j * 16 + y];
        } else {
            const int u = tid - 256;
            float acc = 0.f;
            #pragma unroll
            for (int g = 6; g < 15; ++g) acc += W1[g * 512 + u];
            P.sE1[u]        = 16.f * W1[u] + W1[5 * 512 + u] + 16.f * acc;
            P.sE1[512 + u]  = W1[512 + u];
            P.sE1[1024 + u] = W1[15 * 512 + u];
            P.sE1[1536 + u] = 16.f * W1[2 * 512 + u];
            P.sE1[2048 + u] = W1[3 * 512 + u];
            P.sE1[2560 + u] = W1[4 * 512 + u];
        }
        __syncthreads();

        if (tid < 256) {
            const int t = tid >> 4, y = tid & 15;
            const int tgt = P.s_nbi[y];
            int p = -1;
            #pragma unroll
            for (int q = 0; q < 16; ++q) if (P.s_nbj[t][q] == tgt) p = q;
            P.s_P[t][y] = p;
            unsigned long long bal = __ballot(p >= 0);
            if (y == 0) {
                int vm = (int)((bal >> ((t & 3) * 16)) & 0xFFFFull);
                P.s_vm[t] = vm;
                P.s_m[t]  = (float)__popc(vm);
            }
        } else {
            const int u = tid;
            float acc = 0.f;
            #pragma unroll
            for (int g = 6; g < 15; ++g) acc += W1[g * 512 + u];
            P.sE1[u]        = 16.f * W1[u] + W1[5 * 512 + u] + 16.f * acc;
            P.sE1[512 + u]  = W1[512 + u];
            P.sE1[1024 + u] = W1[15 * 512 + u];
            P.sE1[1536 + u] = 16.f * W1[2 * 512 + u];
            P.sE1[2048 + u] = W1[3 * 512 + u];
            P.sE1[2560 + u] = W1[4 * 512 + u];
        }
        __syncthreads();

        if (tid < 256) {
            const int t = tid >> 4, y = tid & 15, x = t;
            float Y0[16];
            #pragma unroll
            for (int c4 = 0; c4 < 4; ++c4) {
                float4 v = *(const float4*)&P.sX[t][4 * c4];
                Y0[4*c4+0] = v.x; Y0[4*c4+1] = v.y; Y0[4*c4+2] = v.z; Y0[4*c4+3] = v.w;
            }
            float Z4[16], Z5[16];
            #pragma unroll
            for (int c = 0; c < 16; ++c) { Z4[c] = 0.f; Z5[c] = 0.f; }
            #pragma unroll
            for (int tp = 0; tp < 16; ++tp) {
                const int vm = P.s_vm[tp];
                const float mt = P.s_m[tp];
                const float fb = ((vm >> x) & 1) ? mt : 0.f;
                const float f5 = mt * mt;
                #pragma unroll
                for (int c4 = 0; c4 < 4; ++c4) {
                    float4 v = *(const float4*)&P.sX[tp][4 * c4];
                    Z4[4*c4+0] = fmaf(fb, v.x, Z4[4*c4+0]);
                    Z4[4*c4+1] = fmaf(fb, v.y, Z4[4*c4+1]);
                    Z4[4*c4+2] = fmaf(fb, v.z, Z4[4*c4+2]);
                    Z4[4*c4+3] = fmaf(fb, v.w, Z4[4*c4+3]);
                    Z5[4*c4+0] = fmaf(f5, v.x, Z5[4*c4+0]);
                    Z5[4*c4+1] = fmaf(f5, v.y, Z5[4*c4+1]);
                    Z5[4*c4+2] = fmaf(f5, v.z, Z5[4*c4+2]);
                    Z5[4*c4+3] = fmaf(f5, v.w, Z5[4*c4+3]);
                }
            }
            const float m = P.s_m[t];
            float v0a=0.f,v0b=0.f,v1a=0.f,v1b=0.f,v2a=0.f,v2b=0.f;
            float v3a=0.f,v3b=0.f,v4a=0.f,v4b=0.f;
            const float2* Wsb = (const float2*)(P.sE1 + 0 * 512);
            const float2* Wab = (const float2*)(P.sE1 + 1 * 512);
            const float2* W16 = (const float2*)(P.sE1 + 2 * 512);
            const float2* Wtb = (const float2*)(P.sE1 + 4 * 512);
            const float2* Wal = (const float2*)(P.sE1 + 5 * 512);
            #pragma unroll
            for (int c = 0; c < 16; ++c) {
                const float cf0 = m * Y0[c];
                const float cf1 = m * cf0;
                const float cf2 = Y0[c];
                const float cf3 = Z4[c];
                const float cf4 = Z5[c];
                const int idx = c * 16 + y;
                float2 w0 = Wsb[idx]; v0a = fmaf(cf0, w0.x, v0a); v0b = fmaf(cf0, w0.y, v0b);
                float2 w1 = Wab[idx]; v1a = fmaf(cf1, w1.x, v1a); v1b = fmaf(cf1, w1.y, v1b);
                float2 w2 = W16[idx]; v2a = fmaf(cf2, w2.x, v2a); v2b = fmaf(cf2, w2.y, v2b);
                float2 w3 = Wtb[idx]; v3a = fmaf(cf3, w3.x, v3a); v3b = fmaf(cf3, w3.y, v3b);
                float2 w4 = Wal[idx]; v4a = fmaf(cf4, w4.x, v4a); v4b = fmaf(cf4, w4.y, v4b);
            }
            *(float2*)&P.sV[t][0 * 32 + 2 * y] = make_float2(v0a, v0b);
            *(float2*)&P.sV[t][1 * 32 + 2 * y] = make_float2(v1a, v1b);
            *(float2*)&P.sV[t][2 * 32 + 2 * y] = make_float2(v2a, v2b);
            *(float2*)&P.sV[t][3 * 32 + 2 * y] = make_float2(v3a, v3b);
            *(float2*)&P.sV[t][4 * 32 + 2 * y] = make_float2(v4a, v4b);
        } else {
            const int w = tid - 256;
            const int t = w >> 4, y = w & 15, x = t;
            float Z2[16];
            #pragma unroll
            for (int c = 0; c < 16; ++c) Z2[c] = 0.f;
            #pragma unroll
            for (int tp = 0; tp < 16; ++tp) {
                const int vm = P.s_vm[tp];
                const float f2 = (float)((vm >> x) & (vm >> y) & 1);
                #pragma unroll
                for (int c4 = 0; c4 < 4; ++c4) {
                    float4 v = *(const float4*)&P.sX[tp][4 * c4];
                    Z2[4*c4+0] = fmaf(f2, v.x, Z2[4*c4+0]);
                    Z2[4*c4+1] = fmaf(f2, v.y, Z2[4*c4+1]);
                    Z2[4*c4+2] = fmaf(f2, v.z, Z2[4*c4+2]);
                    Z2[4*c4+3] = fmaf(f2, v.w, Z2[4*c4+3]);
                }
            }
            float pp[HH];
            #pragma unroll
            for (int h = 0; h < HH; ++h) pp[h] = 0.f;
            MM_RL(P.sE1 + 3 * 512, 2, Z2[ci], pp);
            float* dst = &P.sPP[(t * 16 + y) * 36];
            #pragma unroll
            for (int h4 = 0; h4 < 8; ++h4)
                *(float4*)&dst[4 * h4] = make_float4(pp[4*h4], pp[4*h4+1], pp[4*h4+2], pp[4*h4+3]);
        }
        __syncthreads();

        float fr[HH];
        if (tid < 256) {
            const int t = tid >> 4, y = tid & 15, x = t;
            const float vy  = (P.s_P[t][y] >= 0) ? 1.f : 0.f;
            const float dxy = (x == y) ? 1.f : 0.f;
            const float* pp = &P.sPP[(t * 16 + y) * 36];
            #pragma unroll
            for (int h4 = 0; h4 < 8; ++h4) {
                const float4 V0 = *(const float4*)&P.sV[t][0 * 32 + 4 * h4];
                const float4 V1 = *(const float4*)&P.sV[t][1 * 32 + 4 * h4];
                const float4 V2 = *(const float4*)&P.sV[t][2 * 32 + 4 * h4];
                const float4 V3 = *(const float4*)&P.sV[t][3 * 32 + 4 * h4];
                const float4 V4 = *(const float4*)&P.sV[t][4 * 32 + 4 * h4];
                const float4 PP = *(const float4*)&pp[4 * h4];
                float a_ = vy*(V0.x+V2.x) + V1.x + V3.x + dxy*V4.x + PP.x + b1[4*h4+0];
                float b_ = vy*(V0.y+V2.y) + V1.y + V3.y + dxy*V4.y + PP.y + b1[4*h4+1];
                float c_ = vy*(V0.z+V2.z) + V1.z + V3.z + dxy*V4.z + PP.z + b1[4*h4+2];
                float d_ = vy*(V0.w+V2.w) + V1.w + V3.w + dxy*V4.w + PP.w + b1[4*h4+3];
                fr[4*h4+0] = a_ > 0.f ? a_ : 0.f;
                fr[4*h4+1] = b_ > 0.f ? b_ : 0.f;
                fr[4*h4+2] = c_ > 0.f ? c_ : 0.f;
                fr[4*h4+3] = d_ > 0.f ? d_ : 0.f;
            }
        }
        __syncthreads();

        if (tid < 256) {
            const int t = tid >> 4, y = tid & 15;
            float* dst = &P.sPP[(y * 16 + t) * 36];
            #pragma unroll
            for (int h4 = 0; h4 < 8; ++h4)
                *(float4*)&dst[4 * h4] = make_float4(fr[4*h4], fr[4*h4+1], fr[4*h4+2], fr[4*h4+3]);
        }
        __syncthreads();

        if (tid < 256) {
            const int q = tid >> 4, p = tid & 15;
            const float* src = &P.sPP[(q * 16 + p) * 36];
            float4* F4 = (float4*)F1c;
            const size_t basec = ((size_t)i * 16 + q) * 128 + p;
            #pragma unroll
            for (int c4 = 0; c4 < 8; ++c4)
                F4[basec + c4 * 16] = *(const float4*)&src[4 * c4];
        }
        __syncthreads();   // drains vmem (barrier semantics) + LDS reuse safety
        if (tid == 0) {
            __threadfence();   // device-scope visibility of F1c tile
            __hip_atomic_store(&flags[i], MAGIC, __ATOMIC_RELEASE,
                               __HIP_MEMORY_SCOPE_AGENT);
        }
    }

    // ================= phase 2: layer 2 (R8 body + flag waits) =============
    {
        Phase2& P = sm.p2;
        const float4* F4 = (const float4*)F1c;

        __syncthreads();
        if (tid < 16) P.s_nbi[tid] = nbrs[i * 16 + tid];
        __syncthreads();

        if (tid < 256) {
            const int t = tid >> 4, y = tid & 15;
            P.s_PQ[t * 17 + y] = nbrs[P.s_nbi[t] * 16 + y];
        } else {
            const int w = tid - 256;
            #pragma unroll
            for (int k = 0; k < 2; ++k) {
                const int u = w + k * 256;
                float acc = 0.f;
                #pragma unroll
                for (int g = 6; g < 15; ++g) acc += W2[g * 1024 + u];
                P.sE2[u]        = 16.f * W2[u] + W2[5 * 1024 + u] + 16.f * acc;
                P.sE2[1024 + u] = W2[1024 + u];
                P.sE2[2048 + u] = W2[15 * 1024 + u];
                P.sE2[3072 + u] = 16.f * W2[2 * 1024 + u];
                P.sE2[4096 + u] = W2[3 * 1024 + u];
                P.sE2[5120 + u] = W2[4 * 1024 + u];
            }
        }
        __syncthreads();

        if (tid < 256) {
            const int t = tid >> 4, y = tid & 15;
            const int tgt = P.s_nbi[y];
            int p = -1;
            #pragma unroll
            for (int q = 0; q < 16; ++q) if (P.s_PQ[t * 17 + q] == tgt) p = q;
            P.s_PQ[t * 17 + y] = p;
        } else {
            const int w = tid - 256;
            #pragma unroll
            for (int k = 2; k < 4; ++k) {
                const int u = w + k * 256;
                float acc = 0.f;
                #pragma unroll
                for (int g = 6; g < 15; ++g) acc += W2[g * 1024 + u];
                P.sE2[u]        = 16.f * W2[u] + W2[5 * 1024 + u] + 16.f * acc;
                P.sE2[1024 + u] = W2[1024 + u];
                P.sE2[2048 + u] = W2[15 * 1024 + u];
                P.sE2[3072 + u] = 16.f * W2[2 * 1024 + u];
                P.sE2[4096 + u] = W2[3 * 1024 + u];
                P.sE2[5120 + u] = W2[4 * 1024 + u];
            }
        }
        // wait for the 16 producer tiles this block consumes
        if (tid < 16) {
            const unsigned* f = &flags[P.s_nbi[tid]];
            while (__hip_atomic_load(f, __ATOMIC_ACQUIRE,
                                     __HIP_MEMORY_SCOPE_AGENT) != MAGIC) {}
        }
        __syncthreads();

        float pre[HH];
        float sab[C2];
        float pp[HH];

        if (tid < 256) {
            const int t = tid >> 4, y = tid & 15;
            const int j = P.s_nbi[t];
            const int p = P.s_PQ[t * 17 + y];
            const float mp = (p >= 0) ? 1.f : 0.f;
            const int pc = p >= 0 ? p : 0;
            const size_t jbase = (size_t)j * 2048;

            float R[C2];
            #pragma unroll
            for (int c = 0; c < C2; ++c) R[c] = 0.f;
            #pragma unroll
            for (int b = 0; b < 16; ++b) {
                const int q = P.s_PQ[t * 17 + b];
                const float mm = (q >= 0) ? mp : 0.f;
                const int qc = q >= 0 ? q : 0;
                const size_t rb = jbase + (size_t)qc * 128 + pc;
                #pragma unroll
                for (int c4 = 0; c4 < 8; ++c4) {
                    float4 v = F4[rb + c4 * 16];
                    R[4*c4+0] = fmaf(mm, v.x, R[4*c4+0]);
                    R[4*c4+1] = fmaf(mm, v.y, R[4*c4+1]);
                    R[4*c4+2] = fmaf(mm, v.z, R[4*c4+2]);
                    R[4*c4+3] = fmaf(mm, v.w, R[4*c4+3]);
                }
            }
            #pragma unroll
            for (int c4 = 0; c4 < 8; ++c4)
                *(float4*)&P.sRpp[(t * 16 + y) * 36 + 4 * c4] =
                    make_float4(R[4*c4+0], R[4*c4+1], R[4*c4+2], R[4*c4+3]);

            #pragma unroll
            for (int h = 0; h < HH; ++h) pre[h] = 0.f;
            MM_RL(P.sE2 + 0 * 1024, 4, R[ci], pre);

            #pragma unroll
            for (int c = 0; c < C2; ++c) {
                float s = R[c];
                s += __shfl_xor(s, 1);
                s += __shfl_xor(s, 2);
                s += __shfl_xor(s, 4);
                s += __shfl_xor(s, 8);
                sab[c] = s;
            }

            float D[C2];
            {
                const size_t db = jbase + (size_t)pc * 128 + pc;
                #pragma unroll
                for (int c4 = 0; c4 < 8; ++c4) {
                    float4 v = F4[db + c4 * 16];
                    D[4*c4+0] = mp * v.x; D[4*c4+1] = mp * v.y;
                    D[4*c4+2] = mp * v.z; D[4*c4+3] = mp * v.w;
                }
            }
            MM_RL(P.sE2 + 2 * 1024, 4, D[ci], pre);
        } else {
            const int w = tid - 256;
            const int g = w >> 4, l = w & 15;
            float ST[C2];
            #pragma unroll
            for (int c = 0; c < C2; ++c) ST[c] = 0.f;
            #pragma unroll
            for (int tp = 0; tp < 16; ++tp) {
                const int jt = P.s_nbi[tp];
                const int py = P.s_PQ[tp * 17 + g];
                const int px = P.s_PQ[tp * 17 + l];
                const float mm = (px >= 0 && py >= 0) ? 1.f : 0.f;
                const int pyc = py >= 0 ? py : 0;
                const int pxc = px >= 0 ? px : 0;
                const size_t rb = (size_t)jt * 2048 + (size_t)pyc * 128 + pxc;
                #pragma unroll
                for (int c4 = 0; c4 < 8; ++c4) {
                    float4 v = F4[rb + c4 * 16];
                    ST[4*c4+0] = fmaf(mm, v.x, ST[4*c4+0]);
                    ST[4*c4+1] = fmaf(mm, v.y, ST[4*c4+1]);
                    ST[4*c4+2] = fmaf(mm, v.z, ST[4*c4+2]);
                    ST[4*c4+3] = fmaf(mm, v.w, ST[4*c4+3]);
                }
            }
            #pragma unroll
            for (int h = 0; h < HH; ++h) pp[h] = 0.f;
            MM_RL(P.sE2 + 3 * 1024, 4, ST[ci], pp);
        }
        __syncthreads();

        if (tid < 256) {
            #pragma unroll
            for (int k = 0; k < 2; ++k) {
                const int x2 = (tid >> 5) + 8 * k;
                const int c = tid & 31;
                float s = 0.f;
                #pragma unroll
                for (int tt = 0; tt < 16; ++tt) s += P.sRpp[(tt * 16 + x2) * 36 + c];
                P.s_stb[x2 * 33 + c] = s;
            }
        }
        __syncthreads();

        if (tid < 256) {
            if (tid < 32) {
                float s = 0.f;
                #pragma unroll
                for (int x2 = 0; x2 < 16; ++x2) s += P.s_stb[x2 * 33 + tid];
                P.s_sall[tid] = s;
            }
        } else {
            const int w = tid - 256;
            const int g = w >> 4, l = w & 15;
            float* dst = &P.sRpp[(l * 16 + g) * 36];
            #pragma unroll
            for (int h4 = 0; h4 < 8; ++h4)
                *(float4*)&dst[4 * h4] = make_float4(pp[4*h4], pp[4*h4+1], pp[4*h4+2], pp[4*h4+3]);
        }
        __syncthreads();

        if (tid < 256) {
            const int t = tid >> 4, y = tid & 15, x = t;
            const float dxy = (x == y) ? 1.f : 0.f;
            float S0 = 0.f, S1 = 0.f, L0 = 0.f, L1 = 0.f;
            {
                const float2* Wab = (const float2*)(P.sE2 + 1 * 1024);
                const float2* Wtb = (const float2*)(P.sE2 + 4 * 1024);
                const float2* Wal = (const float2*)(P.sE2 + 5 * 1024);
                #pragma unroll
                for (int c = 0; c < C2; ++c) {
                    const float cfa = sab[c];
                    const float cft = P.s_stb[t * 33 + c];
                    const float cfl = P.s_sall[c];
                    const int idx = c * 16 + y;
                    float2 wa = Wab[idx]; S0 = fmaf(cfa, wa.x, S0); S1 = fmaf(cfa, wa.y, S1);
                    float2 wt = Wtb[idx]; S0 = fmaf(cft, wt.x, S0); S1 = fmaf(cft, wt.y, S1);
                    float2 wl = Wal[idx]; L0 = fmaf(cfl, wl.x, L0); L1 = fmaf(cfl, wl.y, L1);
                }
            }
            const int gbase = (t & 3) * 16;
            #pragma unroll
            for (int h = 0; h < HH; ++h) {
                const int src = gbase + (h >> 1);
                const float sv = (h & 1) ? S1 : S0;
                const float lv = (h & 1) ? L1 : L0;
                pre[h] += __shfl(sv, src, 64) + dxy * __shfl(lv, src, 64);
            }
            {
                const float* ppr = &P.sRpp[(t * 16 + y) * 36];
                #pragma unroll
                for (int h4 = 0; h4 < 8; ++h4) {
                    const float4 v = *(const float4*)&ppr[4 * h4];
                    pre[4*h4+0] += v.x; pre[4*h4+1] += v.y;
                    pre[4*h4+2] += v.z; pre[4*h4+3] += v.w;
                }
            }
            float local = 0.f;
            #pragma unroll
            for (int h = 0; h < HH; ++h) {
                float v = pre[h] + b2[h];
                v = v > 0.f ? v : 0.f;
                local += v * fcw[h];
            }
            #pragma unroll
            for (int off = 32; off > 0; off >>= 1) local += __shfl_down(local, off, 64);
            if (lane == 0) P.s_red[tid >> 6] = local;
        }
        __syncthreads();
        if (tid == 0) {
            partials[i] = P.s_red[0] + P.s_red[1] + P.s_red[2] + P.s_red[3];
            __threadfence();
            __hip_atomic_store(&dflags[i], MAGIC, __ATOMIC_RELEASE,
                               __HIP_MEMORY_SCOPE_AGENT);
        }
    }

    // ================= final reduce: block 0 only =================
    if (blockIdx.x == 0) {
        if (tid < 256) {
            const unsigned* f = &dflags[tid];
            while (__hip_atomic_load(f, __ATOMIC_ACQUIRE,
                                     __HIP_MEMORY_SCOPE_AGENT) != MAGIC) {}
        }
        __syncthreads();
        float local = (tid < 256) ? partials[tid] : 0.f;
        #pragma unroll
        for (int off = 32; off > 0; off >>= 1) local += __shfl_down(local, off, 64);
        if ((tid & 63) == 0) s_fin[tid >> 6] = local;
        __syncthreads();
        if (tid == 0) {
            float s = 0.f;
            #pragma unroll
            for (int w = 0; w < 8; ++w) s += s_fin[w];
            out[0] = s + fcb[0];
        }
    }
}

extern "C" void kernel_launch(void* const* d_in, const int* in_sizes, int n_in,
                              void* d_out, int out_size, void* d_ws, size_t ws_size,
                              hipStream_t stream) {
    const float* X    = (const float*)d_in[0];
    const int*   nbrs = (const int*)  d_in[1];
    const float* W1   = (const float*)d_in[2];
    const float* b1   = (const float*)d_in[3];
    const float* W2   = (const float*)d_in[4];
    const float* b2   = (const float*)d_in[5];
    const float* fc_w = (const float*)d_in[6];
    const float* fc_b = (const float*)d_in[7];
    float* outp = (float*)d_out;

    float*    F1c      = (float*)d_ws;                         // 8 MB
    unsigned* flags    = (unsigned*)(F1c + (size_t)NV * KN * KN * HH);
    float*    partials = (float*)(flags + NV);
    unsigned* dflags   = (unsigned*)(partials + NV);

    ccn_fused<<<NV, 512, 0, stream>>>(X, nbrs, W1, b1, W2, b2, fc_w, fc_b,
                                      F1c, flags, partials, dflags, outp);
}

// Round 11
// 106.186 us; speedup vs baseline: 1.1525x; 1.1525x over previous
//
#include <hip/hip_runtime.h>

// CCN_2D on MI355X. N=256 vertices, K=16, C0=16, H=32.
// Facts (validated by exact passes R1-R10):
//  * CH rows one-hot => T_t[a][b][c] = Fin[j_t, P_t[a], P_t[b], c].
//  * A = I_16 collapses contract18 to 6 effective weight matrices.
//  * P_t[t] = -1 (no self-loops) => c17 / d_ttt terms vanish.
//  * Layer-1 input is broadcast of X => rank-1 closed form, no gathers.
//  * F1 channel-interleaved: chunk (i*16+q)*128 + c4*16 + p holds channels
//    4c4..4c4+3 of F1[i][p][q][:] (16 B stride on lane-varying p).
// Structure ladder (measured): 2 plain launches (R6, 107.7) beats 3 launches
// (113.9), coop launch (154.5), and 1 launch w/ device-scope flags (122.4).
// This round: R6 verbatim + l1 tail simplification — half-B parks Wt2
// results channel-major (sPP2[h4][cell][4]: writer AND reader conflict-free),
// output thread remapped to (q,p) computing its cell directly from LDS;
// removes 2 barriers + the register park + conflicted LDS round-trip.

constexpr int KN = 16, HH = 32, NV = 256, C2 = 32;

__device__ __forceinline__ float rlane(float v, int l) {
    return __int_as_float(__builtin_amdgcn_readlane(__float_as_int(v), l));
}

// ACC[h] += COEF(ci) * W[ci][h], ci in [0, 8*NB), W row-major [c][32] (LDS ok).
// Wave-coalesced weight load (float4/lane) + readlane broadcast. All 64 lanes
// of the executing wave must be active.
#define MM_RL(WPTR, NB, COEF_EXPR, ACC) do {                                   \
    _Pragma("unroll")                                                          \
    for (int B = 0; B < (NB); ++B) {                                           \
        const float4 w_ = ((const float4*)(WPTR))[B * 64 + lane];              \
        _Pragma("unroll")                                                      \
        for (int cc = 0; cc < 8; ++cc) {                                       \
            const int ci = B * 8 + cc;                                         \
            const float cf_ = (COEF_EXPR);                                     \
            _Pragma("unroll")                                                  \
            for (int h4 = 0; h4 < 8; ++h4) {                                   \
                const int src_ = 8 * cc + h4;                                  \
                (ACC)[4*h4+0] = fmaf(cf_, rlane(w_.x, src_), (ACC)[4*h4+0]);   \
                (ACC)[4*h4+1] = fmaf(cf_, rlane(w_.y, src_), (ACC)[4*h4+1]);   \
                (ACC)[4*h4+2] = fmaf(cf_, rlane(w_.z, src_), (ACC)[4*h4+2]);   \
                (ACC)[4*h4+3] = fmaf(cf_, rlane(w_.w, src_), (ACC)[4*h4+3]);   \
            }                                                                  \
        }                                                                      \
    }                                                                          \
} while (0)

// ---------------- layer 1 ----------------
// E1 slices (512 floats each): 0:Wsb 1:Wab 2:W16 3:Wt2 4:Wtb 5:Wal
// pre = vy*(m*Y0.Wsb) + (m^2*Y0).Wab + vy*(Y0.W16) + Z2.Wt2 + Z4.Wtb + dxy*Z5.Wal
// Output layout (float4 chunks): F1c chunk index = (i*16+q)*128 + c4*16 + p,
// holding channels c4*4..c4*4+3 of logical F1[i][p][q][:]. (q,p) = (y,x).
__global__ __launch_bounds__(512)
void ccn_l1(const float* __restrict__ X, const int* __restrict__ nbrs,
            const float* __restrict__ W1, const float* __restrict__ bias,
            float* __restrict__ F1c, float* __restrict__ outz)
{
    __shared__ float sE1[6 * 512];       // 12 KB
    __shared__ float sPP2[8 * 256 * 4];  // 32 KB, channel-major [h4][cell][4]
    __shared__ float sX[16][20];
    __shared__ float sV[16][164];        // 5 matvec results x 32 per group
    __shared__ int   s_nbi[16];
    __shared__ int   s_nbj[16][17];
    __shared__ int   s_P[16][16];
    __shared__ int   s_vm[16];
    __shared__ float s_m[16];

    const int tid  = threadIdx.x;
    const int i    = ((blockIdx.x & 7) << 5) | (blockIdx.x >> 3);  // XCD swizzle
    const int lane = tid & 63;

    if (blockIdx.x == 0 && tid == 0) outz[0] = 0.f;   // zero accumulator for l2
    if (tid < 16) s_nbi[tid] = nbrs[i * 16 + tid];
    __syncthreads();  // B0

    if (tid < 256) {
        const int t = tid >> 4, y = tid & 15;
        const int j = s_nbi[t];
        s_nbj[t][y] = nbrs[j * 16 + y];
        sX[t][y]    = X[j * 16 + y];
    } else {
        const int u = tid - 256;       // E1 entries 0..255
        float acc = 0.f;
        #pragma unroll
        for (int g = 6; g < 15; ++g) acc += W1[g * 512 + u];
        sE1[u]        = 16.f * W1[u] + W1[5 * 512 + u] + 16.f * acc;
        sE1[512 + u]  = W1[512 + u];
        sE1[1024 + u] = W1[15 * 512 + u];
        sE1[1536 + u] = 16.f * W1[2 * 512 + u];
        sE1[2048 + u] = W1[3 * 512 + u];
        sE1[2560 + u] = W1[4 * 512 + u];
    }
    __syncthreads();  // B1

    if (tid < 256) {
        const int t = tid >> 4, y = tid & 15;
        const int tgt = s_nbi[y];
        int p = -1;
        #pragma unroll
        for (int q = 0; q < 16; ++q) if (s_nbj[t][q] == tgt) p = q;
        s_P[t][y] = p;
        unsigned long long bal = __ballot(p >= 0);
        if (y == 0) {
            int vm = (int)((bal >> ((t & 3) * 16)) & 0xFFFFull);
            s_vm[t] = vm;
            s_m[t]  = (float)__popc(vm);
        }
    } else {
        const int u = tid;             // E1 entries 256..511
        float acc = 0.f;
        #pragma unroll
        for (int g = 6; g < 15; ++g) acc += W1[g * 512 + u];
        sE1[u]        = 16.f * W1[u] + W1[5 * 512 + u] + 16.f * acc;
        sE1[512 + u]  = W1[512 + u];
        sE1[1024 + u] = W1[15 * 512 + u];
        sE1[1536 + u] = 16.f * W1[2 * 512 + u];
        sE1[2048 + u] = W1[3 * 512 + u];
        sE1[2560 + u] = W1[4 * 512 + u];
    }
    __syncthreads();  // B2

    if (tid < 256) {
        // ---- half A: Z4/Z5 + 5 cooperative matvecs (lane y -> h=2y,2y+1) ----
        const int t = tid >> 4, y = tid & 15, x = t;
        float Y0[16];
        #pragma unroll
        for (int c4 = 0; c4 < 4; ++c4) {
            float4 v = *(const float4*)&sX[t][4 * c4];
            Y0[4*c4+0] = v.x; Y0[4*c4+1] = v.y; Y0[4*c4+2] = v.z; Y0[4*c4+3] = v.w;
        }
        float Z4[16], Z5[16];
        #pragma unroll
        for (int c = 0; c < 16; ++c) { Z4[c] = 0.f; Z5[c] = 0.f; }
        #pragma unroll
        for (int tp = 0; tp < 16; ++tp) {
            const int vm = s_vm[tp];
            const float mt = s_m[tp];
            const float fb = ((vm >> x) & 1) ? mt : 0.f;
            const float f5 = mt * mt;
            #pragma unroll
            for (int c4 = 0; c4 < 4; ++c4) {
                float4 v = *(const float4*)&sX[tp][4 * c4];
                Z4[4*c4+0] = fmaf(fb, v.x, Z4[4*c4+0]);
                Z4[4*c4+1] = fmaf(fb, v.y, Z4[4*c4+1]);
                Z4[4*c4+2] = fmaf(fb, v.z, Z4[4*c4+2]);
                Z4[4*c4+3] = fmaf(fb, v.w, Z4[4*c4+3]);
                Z5[4*c4+0] = fmaf(f5, v.x, Z5[4*c4+0]);
                Z5[4*c4+1] = fmaf(f5, v.y, Z5[4*c4+1]);
                Z5[4*c4+2] = fmaf(f5, v.z, Z5[4*c4+2]);
                Z5[4*c4+3] = fmaf(f5, v.w, Z5[4*c4+3]);
            }
        }
        const float m = s_m[t];
        float v0a=0.f,v0b=0.f,v1a=0.f,v1b=0.f,v2a=0.f,v2b=0.f;
        float v3a=0.f,v3b=0.f,v4a=0.f,v4b=0.f;
        const float2* Wsb = (const float2*)(sE1 + 0 * 512);
        const float2* Wab = (const float2*)(sE1 + 1 * 512);
        const float2* W16 = (const float2*)(sE1 + 2 * 512);
        const float2* Wtb = (const float2*)(sE1 + 4 * 512);
        const float2* Wal = (const float2*)(sE1 + 5 * 512);
        #pragma unroll
        for (int c = 0; c < 16; ++c) {
            const float cf0 = m * Y0[c];
            const float cf1 = m * cf0;
            const float cf2 = Y0[c];
            const float cf3 = Z4[c];
            const float cf4 = Z5[c];
            const int idx = c * 16 + y;
            float2 w0 = Wsb[idx]; v0a = fmaf(cf0, w0.x, v0a); v0b = fmaf(cf0, w0.y, v0b);
            float2 w1 = Wab[idx]; v1a = fmaf(cf1, w1.x, v1a); v1b = fmaf(cf1, w1.y, v1b);
            float2 w2 = W16[idx]; v2a = fmaf(cf2, w2.x, v2a); v2b = fmaf(cf2, w2.y, v2b);
            float2 w3 = Wtb[idx]; v3a = fmaf(cf3, w3.x, v3a); v3b = fmaf(cf3, w3.y, v3b);
            float2 w4 = Wal[idx]; v4a = fmaf(cf4, w4.x, v4a); v4b = fmaf(cf4, w4.y, v4b);
        }
        *(float2*)&sV[t][0 * 32 + 2 * y] = make_float2(v0a, v0b);
        *(float2*)&sV[t][1 * 32 + 2 * y] = make_float2(v1a, v1b);
        *(float2*)&sV[t][2 * 32 + 2 * y] = make_float2(v2a, v2b);
        *(float2*)&sV[t][3 * 32 + 2 * y] = make_float2(v3a, v3b);
        *(float2*)&sV[t][4 * 32 + 2 * y] = make_float2(v4a, v4b);
    } else {
        // ---- half B: Z2 + Wt2 readlane-matmul, park channel-major ----
        const int w = tid - 256;
        const int t = w >> 4, y = w & 15, x = t;
        float Z2[16];
        #pragma unroll
        for (int c = 0; c < 16; ++c) Z2[c] = 0.f;
        #pragma unroll
        for (int tp = 0; tp < 16; ++tp) {
            const int vm = s_vm[tp];
            const float f2 = (float)((vm >> x) & (vm >> y) & 1);
            #pragma unroll
            for (int c4 = 0; c4 < 4; ++c4) {
                float4 v = *(const float4*)&sX[tp][4 * c4];
                Z2[4*c4+0] = fmaf(f2, v.x, Z2[4*c4+0]);
                Z2[4*c4+1] = fmaf(f2, v.y, Z2[4*c4+1]);
                Z2[4*c4+2] = fmaf(f2, v.z, Z2[4*c4+2]);
                Z2[4*c4+3] = fmaf(f2, v.w, Z2[4*c4+3]);
            }
        }
        float pp[HH];
        #pragma unroll
        for (int h = 0; h < HH; ++h) pp[h] = 0.f;
        MM_RL(sE1 + 3 * 512, 2, Z2[ci], pp);
        // park: sPP2[h4][cell][4], cell = y*16 + x wait NO: cell keyed as
        // (y_out*16 + x_out) = (y*16 + t) so reader (q,p) hits (q*16+p).
        const int cell = y * 16 + t;
        #pragma unroll
        for (int h4 = 0; h4 < 8; ++h4)
            *(float4*)&sPP2[(h4 * 256 + cell) * 4] =
                make_float4(pp[4*h4], pp[4*h4+1], pp[4*h4+2], pp[4*h4+3]);
    }
    __syncthreads();  // B3 (sV + sPP2 + s_P ready) — final barrier

    if (tid < 256) {
        // output thread (q,p) computes cell (x=p, y=q) and stores directly:
        // chunk (i*16+q)*128 + h4*16 + p  -> p lane-varying, 256 B coalesced.
        const int q = tid >> 4, p = tid & 15;
        const float vy  = (s_P[p][q] >= 0) ? 1.f : 0.f;
        const float dxy = (p == q) ? 1.f : 0.f;
        float4* F4 = (float4*)F1c;
        const size_t basec = ((size_t)i * 16 + q) * 128 + p;
        #pragma unroll
        for (int h4 = 0; h4 < 8; ++h4) {
            const float4 V0 = *(const float4*)&sV[p][0 * 32 + 4 * h4];
            const float4 V1 = *(const float4*)&sV[p][1 * 32 + 4 * h4];
            const float4 V2 = *(const float4*)&sV[p][2 * 32 + 4 * h4];
            const float4 V3 = *(const float4*)&sV[p][3 * 32 + 4 * h4];
            const float4 V4 = *(const float4*)&sV[p][4 * 32 + 4 * h4];
            const float4 PP = *(const float4*)&sPP2[(h4 * 256 + q * 16 + p) * 4];
            float a_ = vy*(V0.x+V2.x) + V1.x + V3.x + dxy*V4.x + PP.x + bias[4*h4+0];
            float b_ = vy*(V0.y+V2.y) + V1.y + V3.y + dxy*V4.y + PP.y + bias[4*h4+1];
            float c_ = vy*(V0.z+V2.z) + V1.z + V3.z + dxy*V4.z + PP.z + bias[4*h4+2];
            float d_ = vy*(V0.w+V2.w) + V1.w + V3.w + dxy*V4.w + PP.w + bias[4*h4+3];
            F4[basec + h4 * 16] = make_float4(a_ > 0.f ? a_ : 0.f, b_ > 0.f ? b_ : 0.f,
                                              c_ > 0.f ? c_ : 0.f, d_ > 0.f ? d_ : 0.f);
        }
    }
}

// ---------------- layer 2 (R6 verbatim) ----------------
// E2 slices (1024 floats each): 0:Wsb 1:Wab 2:W16 3:Wt2 4:Wtb 5:Wal
// F1c chunk (j*16+q)*128 + c4*16 + p = channels 4c4..4c4+3 of F1[j][p][q][:].
__global__ __launch_bounds__(512)
void ccn_l2(const float* __restrict__ F1c, const int* __restrict__ nbrs,
            const float* __restrict__ W2, const float* __restrict__ bias,
            const float* __restrict__ fcw, const float* __restrict__ fcb,
            float* __restrict__ out)
{
    __shared__ float sE2[6 * 1024];    // 24 KB
    __shared__ float sRpp[256 * 36];   // 36 KB: R rows, then half-B pp results
    __shared__ float s_stb[16 * 33];
    __shared__ float s_sall[C2];
    __shared__ int   s_nbi[16];
    __shared__ int   s_PQ[16 * 17];    // nbj, then overwritten with P (wave-local)
    __shared__ float s_red[4];

    const int tid  = threadIdx.x;
    const int i    = ((blockIdx.x & 7) << 5) | (blockIdx.x >> 3);  // XCD swizzle
    const int lane = tid & 63;
    const float4* F4 = (const float4*)F1c;

    if (tid < 16) s_nbi[tid] = nbrs[i * 16 + tid];
    __syncthreads();  // B0

    if (tid < 256) {
        const int t = tid >> 4, y = tid & 15;
        const int j = s_nbi[t];
        s_PQ[t * 17 + y] = nbrs[j * 16 + y];
    } else {
        const int w = tid - 256;
        #pragma unroll
        for (int k = 0; k < 2; ++k) {
            const int u = w + k * 256;          // E2 entries 0..511
            float acc = 0.f;
            #pragma unroll
            for (int g = 6; g < 15; ++g) acc += W2[g * 1024 + u];
            sE2[u]        = 16.f * W2[u] + W2[5 * 1024 + u] + 16.f * acc;
            sE2[1024 + u] = W2[1024 + u];
            sE2[2048 + u] = W2[15 * 1024 + u];
            sE2[3072 + u] = 16.f * W2[2 * 1024 + u];
            sE2[4096 + u] = W2[3 * 1024 + u];
            sE2[5120 + u] = W2[4 * 1024 + u];
        }
    }
    __syncthreads();  // B1

    if (tid < 256) {
        const int t = tid >> 4, y = tid & 15;
        const int tgt = s_nbi[y];
        int p = -1;
        #pragma unroll
        for (int q = 0; q < 16; ++q) if (s_PQ[t * 17 + q] == tgt) p = q;
        s_PQ[t * 17 + y] = p;   // overwrite: reads above precede write (wave lockstep)
    } else {
        const int w = tid - 256;
        #pragma unroll
        for (int k = 2; k < 4; ++k) {
            const int u = w + k * 256;          // E2 entries 512..1023
            float acc = 0.f;
            #pragma unroll
            for (int g = 6; g < 15; ++g) acc += W2[g * 1024 + u];
            sE2[u]        = 16.f * W2[u] + W2[5 * 1024 + u] + 16.f * acc;
            sE2[1024 + u] = W2[1024 + u];
            sE2[2048 + u] = W2[15 * 1024 + u];
            sE2[3072 + u] = 16.f * W2[2 * 1024 + u];
            sE2[4096 + u] = W2[3 * 1024 + u];
            sE2[5120 + u] = W2[4 * 1024 + u];
        }
    }
    __syncthreads();  // B2

    float pre[HH];
    float sab[C2];
    float pp[HH];

    if (tid < 256) {
        // ---- half A: R gather + Wsb/W16 readlane matmuls ----
        const int t = tid >> 4, y = tid & 15;
        const int j = s_nbi[t];
        const int p = s_PQ[t * 17 + y];
        const float mp = (p >= 0) ? 1.f : 0.f;
        const int pc = p >= 0 ? p : 0;
        const size_t jbase = (size_t)j * 2048;   // 16*128 chunks per tile

        float R[C2];
        #pragma unroll
        for (int c = 0; c < C2; ++c) R[c] = 0.f;
        #pragma unroll
        for (int b = 0; b < 16; ++b) {
            const int q = s_PQ[t * 17 + b];
            const float mm = (q >= 0) ? mp : 0.f;
            const int qc = q >= 0 ? q : 0;
            const size_t rb = jbase + (size_t)qc * 128 + pc;
            #pragma unroll
            for (int c4 = 0; c4 < 8; ++c4) {
                float4 v = F4[rb + c4 * 16];
                R[4*c4+0] = fmaf(mm, v.x, R[4*c4+0]);
                R[4*c4+1] = fmaf(mm, v.y, R[4*c4+1]);
                R[4*c4+2] = fmaf(mm, v.z, R[4*c4+2]);
                R[4*c4+3] = fmaf(mm, v.w, R[4*c4+3]);
            }
        }
        #pragma unroll
        for (int c4 = 0; c4 < 8; ++c4)
            *(float4*)&sRpp[(t * 16 + y) * 36 + 4 * c4] =
                make_float4(R[4*c4+0], R[4*c4+1], R[4*c4+2], R[4*c4+3]);

        #pragma unroll
        for (int h = 0; h < HH; ++h) pre[h] = 0.f;
        MM_RL(sE2 + 0 * 1024, 4, R[ci], pre);          // Wsb^T R

        #pragma unroll
        for (int c = 0; c < C2; ++c) {
            float s = R[c];
            s += __shfl_xor(s, 1);
            s += __shfl_xor(s, 2);
            s += __shfl_xor(s, 4);
            s += __shfl_xor(s, 8);
            sab[c] = s;
        }

        float D[C2];
        {
            const size_t db = jbase + (size_t)pc * 128 + pc;
            #pragma unroll
            for (int c4 = 0; c4 < 8; ++c4) {
                float4 v = F4[db + c4 * 16];
                D[4*c4+0] = mp * v.x; D[4*c4+1] = mp * v.y;
                D[4*c4+2] = mp * v.z; D[4*c4+3] = mp * v.w;
            }
        }
        MM_RL(sE2 + 2 * 1024, 4, D[ci], pre);          // W16^T D
    } else {
        // ---- half B: ST gather + Wt2 readlane matmul ----
        const int w = tid - 256;
        const int g = w >> 4, l = w & 15;              // output (x=l, y=g)
        float ST[C2];
        #pragma unroll
        for (int c = 0; c < C2; ++c) ST[c] = 0.f;
        #pragma unroll
        for (int tp = 0; tp < 16; ++tp) {
            const int jt = s_nbi[tp];
            const int py = s_PQ[tp * 17 + g];          // group-uniform
            const int px = s_PQ[tp * 17 + l];          // lane-varying
            const float mm = (px >= 0 && py >= 0) ? 1.f : 0.f;
            const int pyc = py >= 0 ? py : 0;
            const int pxc = px >= 0 ? px : 0;
            const size_t rb = (size_t)jt * 2048 + (size_t)pyc * 128 + pxc;
            #pragma unroll
            for (int c4 = 0; c4 < 8; ++c4) {
                float4 v = F4[rb + c4 * 16];
                ST[4*c4+0] = fmaf(mm, v.x, ST[4*c4+0]);
                ST[4*c4+1] = fmaf(mm, v.y, ST[4*c4+1]);
                ST[4*c4+2] = fmaf(mm, v.z, ST[4*c4+2]);
                ST[4*c4+3] = fmaf(mm, v.w, ST[4*c4+3]);
            }
        }
        #pragma unroll
        for (int h = 0; h < HH; ++h) pp[h] = 0.f;
        MM_RL(sE2 + 3 * 1024, 4, ST[ci], pp);          // Wt2^T ST
    }
    __syncthreads();  // B3  (sR rows complete)

    if (tid < 256) {
        // stb[x2][c] = sum_t R[t][x2][c]
        #pragma unroll
        for (int k = 0; k < 2; ++k) {
            const int x2 = (tid >> 5) + 8 * k;
            const int c = tid & 31;
            float s = 0.f;
            #pragma unroll
            for (int tt = 0; tt < 16; ++tt) s += sRpp[(tt * 16 + x2) * 36 + c];
            s_stb[x2 * 33 + c] = s;
        }
    }
    __syncthreads();  // B4  (stb complete; sR now dead)

    if (tid < 256) {
        if (tid < 32) {
            float s = 0.f;
            #pragma unroll
            for (int x2 = 0; x2 < 16; ++x2) s += s_stb[x2 * 33 + tid];
            s_sall[tid] = s;
        }
    } else {
        // half B parks its pp into the dead sR buffer at row x*16+y = l*16+g
        const int w = tid - 256;
        const int g = w >> 4, l = w & 15;
        float* dst = &sRpp[(l * 16 + g) * 36];
        #pragma unroll
        for (int h4 = 0; h4 < 8; ++h4)
            *(float4*)&dst[4 * h4] = make_float4(pp[4*h4], pp[4*h4+1], pp[4*h4+2], pp[4*h4+3]);
    }
    __syncthreads();  // B5

    if (tid < 256) {
        const int t = tid >> 4, y = tid & 15, x = t;
        const float dxy = (x == y) ? 1.f : 0.f;
        // cooperative matvecs Wab/Wtb/Wal (lane y -> h=2y,2y+1), combine via shfl
        float S0 = 0.f, S1 = 0.f, L0 = 0.f, L1 = 0.f;
        {
            const float2* Wab = (const float2*)(sE2 + 1 * 1024);
            const float2* Wtb = (const float2*)(sE2 + 4 * 1024);
            const float2* Wal = (const float2*)(sE2 + 5 * 1024);
            #pragma unroll
            for (int c = 0; c < C2; ++c) {
                const float cfa = sab[c];
                const float cft = s_stb[t * 33 + c];
                const float cfl = s_sall[c];
                const int idx = c * 16 + y;
                float2 wa = Wab[idx]; S0 = fmaf(cfa, wa.x, S0); S1 = fmaf(cfa, wa.y, S1);
                float2 wt = Wtb[idx]; S0 = fmaf(cft, wt.x, S0); S1 = fmaf(cft, wt.y, S1);
                float2 wl = Wal[idx]; L0 = fmaf(cfl, wl.x, L0); L1 = fmaf(cfl, wl.y, L1);
            }
        }
        const int gbase = (t & 3) * 16;
        #pragma unroll
        for (int h = 0; h < HH; ++h) {
            const int src = gbase + (h >> 1);
            const float sv = (h & 1) ? S1 : S0;
            const float lv = (h & 1) ? L1 : L0;
            pre[h] += __shfl(sv, src, 64) + dxy * __shfl(lv, src, 64);
        }
        // pick up half B's Wt2 contribution (row t*16+y)
        {
            const float* ppr = &sRpp[(t * 16 + y) * 36];
            #pragma unroll
            for (int h4 = 0; h4 < 8; ++h4) {
                const float4 v = *(const float4*)&ppr[4 * h4];
                pre[4*h4+0] += v.x; pre[4*h4+1] += v.y;
                pre[4*h4+2] += v.z; pre[4*h4+3] += v.w;
            }
        }
        // epilogue: bias, relu, dot fcw, wave reduce
        float local = 0.f;
        #pragma unroll
        for (int h = 0; h < HH; ++h) {
            float v = pre[h] + bias[h];
            v = v > 0.f ? v : 0.f;
            local += v * fcw[h];
        }
        #pragma unroll
        for (int off = 32; off > 0; off >>= 1) local += __shfl_down(local, off, 64);
        if (lane == 0) s_red[tid >> 6] = local;
    }
    __syncthreads();  // B6
    if (tid == 0) {
        const float v = s_red[0] + s_red[1] + s_red[2] + s_red[3]
                      + fcb[0] * (1.f / 256.f);
        atomicAdd(out, v);
    }
}

extern "C" void kernel_launch(void* const* d_in, const int* in_sizes, int n_in,
                              void* d_out, int out_size, void* d_ws, size_t ws_size,
                              hipStream_t stream) {
    const float* X    = (const float*)d_in[0];
    const int*   nbrs = (const int*)  d_in[1];
    const float* W1   = (const float*)d_in[2];
    const float* b1   = (const float*)d_in[3];
    const float* W2   = (const float*)d_in[4];
    const float* b2   = (const float*)d_in[5];
    const float* fc_w = (const float*)d_in[6];
    const float* fc_b = (const float*)d_in[7];
    float* outp = (float*)d_out;

    float* F1c = (float*)d_ws;   // 256*16*16*32 floats = 8 MB

    ccn_l1<<<NV, 512, 0, stream>>>(X, nbrs, W1, b1, F1c, outp);
    ccn_l2<<<NV, 512, 0, stream>>>(F1c, nbrs, W2, b2, fc_w, fc_b, outp);
}